// Round 3
// baseline (2516.238 us; speedup 1.0000x reference)
//
#include <hip/hip_runtime.h>
#include <math.h>

// ---- problem constants ----
#define NSTREAM 4
#define KHEADS  3
#define SLOTS   7
#define DH      128
#define DD      896        // D = S*DH
#define HH      12         // N*K heads
#define IO      768
#define MIX     3584
#define BB      4
#define TT      1024
#define BT      4096       // B*T
#define NBT     16384      // N*B*T
#define ZSZ     (NSTREAM*BT*DD)   // 14,680,064 floats
#define QSZ     (BB*HH*TT*DH)     // 6,291,456 floats

typedef __attribute__((ext_vector_type(8))) short bf16x8;   // 8 bf16 = 4 VGPR
typedef __attribute__((ext_vector_type(4))) float f32x4;    // MFMA acc

__device__ __forceinline__ float gelu_exact(float x){
    return 0.5f * x * (1.0f + erff(x * 0.70710678118654752f));
}

// fp32 -> bf16 hi (RNE) + bf16 lo (truncated residual).  |x - hi - lo| ~ 2^-17 |x|
__device__ __forceinline__ void split1(float x, unsigned &hi, unsigned &lo){
    unsigned u = __float_as_uint(x);
    unsigned r = u + 0x7FFFu + ((u >> 16) & 1u);
    hi = r >> 16;
    float hf = __uint_as_float(r & 0xFFFF0000u);
    float l = x - hf;
    lo = __float_as_uint(l) >> 16;
}

__device__ __forceinline__ void pack8(const float4 &f0, const float4 &f1,
                                      uint4 &ph, uint4 &pl){
    unsigned h0,h1,l0,l1;
    split1(f0.x,h0,l0); split1(f0.y,h1,l1); ph.x = h0|(h1<<16); pl.x = l0|(l1<<16);
    split1(f0.z,h0,l0); split1(f0.w,h1,l1); ph.y = h0|(h1<<16); pl.y = l0|(l1<<16);
    split1(f1.x,h0,l0); split1(f1.y,h1,l1); ph.z = h0|(h1<<16); pl.z = l0|(l1<<16);
    split1(f1.z,h0,l0); split1(f1.w,h1,l1); ph.w = h0|(h1<<16); pl.w = l0|(l1<<16);
}

// ---------------------------------------------------------------------------
// Row statistics for LayerNorm fusion: mean and rsqrt(var+eps) per 896-row.
// ---------------------------------------------------------------------------
__global__ __launch_bounds__(256)
void rowstats(const float* __restrict__ X, float* __restrict__ st)
{
    const int r = blockIdx.x;
    const float* xp = X + (size_t)r * DD;
    const int tid = threadIdx.x;
    float s = 0.f, sq = 0.f;
    if (tid < 224){
        float4 v = *(const float4*)(xp + tid*4);
        s  = v.x + v.y + v.z + v.w;
        sq = v.x*v.x + v.y*v.y + v.z*v.z + v.w*v.w;
    }
    #pragma unroll
    for (int off = 32; off >= 1; off >>= 1){
        s  += __shfl_down(s,  off);
        sq += __shfl_down(sq, off);
    }
    __shared__ float ps[4], pq[4];
    if ((tid & 63) == 0){ ps[tid>>6] = s; pq[tid>>6] = sq; }
    __syncthreads();
    if (tid == 0){
        s  = ps[0]+ps[1]+ps[2]+ps[3];
        sq = pq[0]+pq[1]+pq[2]+pq[3];
        float mean = s * (1.0f/DD);
        float var  = sq * (1.0f/DD) - mean*mean;
        st[2*r]   = mean;
        st[2*r+1] = rsqrtf(var + 1e-5f);
    }
}

// ---------------------------------------------------------------------------
// fp32 NT GEMM (VALU), kept for the encoder only (5.6 GF).
// MODE 0: writes z[nn] = acc + stream_bias[nn] for the 4 streams.
// ---------------------------------------------------------------------------
template<int MODE>
__global__ __launch_bounds__(256)
void gemm_nt(const float* __restrict__ A, const float* __restrict__ Bw,
             float* __restrict__ C, int K,
             const float* __restrict__ bias)
{
    __shared__ float As[8][128];
    __shared__ float Bs[8][128];
    const int tid = threadIdx.x;
    const int tx = tid & 15, ty = tid >> 4;
    const int m0 = blockIdx.x * 128, n0 = blockIdx.y * 128;
    const int lrow = tid >> 1;
    const int lk   = (tid & 1) * 4;
    const float* Ap = A  + (size_t)(m0 + lrow) * K + lk;
    const float* Bp = Bw + (size_t)(n0 + lrow) * K + lk;

    float acc[8][8];
    #pragma unroll
    for (int i=0;i<8;i++)
        #pragma unroll
        for (int j=0;j<8;j++) acc[i][j] = 0.f;

    for (int k0 = 0; k0 < K; k0 += 8){
        float4 av = *(const float4*)(Ap + k0);
        float4 bv = *(const float4*)(Bp + k0);
        As[lk+0][lrow]=av.x; As[lk+1][lrow]=av.y; As[lk+2][lrow]=av.z; As[lk+3][lrow]=av.w;
        Bs[lk+0][lrow]=bv.x; Bs[lk+1][lrow]=bv.y; Bs[lk+2][lrow]=bv.z; Bs[lk+3][lrow]=bv.w;
        __syncthreads();
        #pragma unroll
        for (int kk = 0; kk < 8; ++kk){
            float a[8], b[8];
            *(float4*)(a)   = *(const float4*)&As[kk][ty*8];
            *(float4*)(a+4) = *(const float4*)&As[kk][ty*8+4];
            *(float4*)(b)   = *(const float4*)&Bs[kk][tx*8];
            *(float4*)(b+4) = *(const float4*)&Bs[kk][tx*8+4];
            #pragma unroll
            for (int i=0;i<8;i++)
                #pragma unroll
                for (int j=0;j<8;j++) acc[i][j] = fmaf(a[i], b[j], acc[i][j]);
        }
        __syncthreads();
    }

    const int rm = m0 + ty*8, rn = n0 + tx*8;
    #pragma unroll
    for (int nn = 0; nn < NSTREAM; ++nn){
        float4 s0 = *(const float4*)(bias + nn*DD + rn);
        float4 s1 = *(const float4*)(bias + nn*DD + rn + 4);
        #pragma unroll
        for (int i=0;i<8;i++){
            float* cp = C + (size_t)(nn*BT + rm + i)*DD + rn;
            float4 o0, o1;
            o0.x=acc[i][0]+s0.x; o0.y=acc[i][1]+s0.y; o0.z=acc[i][2]+s0.z; o0.w=acc[i][3]+s0.w;
            o1.x=acc[i][4]+s1.x; o1.y=acc[i][5]+s1.y; o1.z=acc[i][6]+s1.z; o1.w=acc[i][7]+s1.w;
            *(float4*)cp = o0; *(float4*)(cp+4) = o1;
        }
    }
}

// ---------------------------------------------------------------------------
// bf16x3 split-MFMA NT GEMM:  C[m,n] = sum_k A[m,k]*B[n,k]  (fp32-accurate)
// A,B fp32 in HBM; staged to LDS as (hi,lo) bf16 pairs.
// acc += Ahi*Bhi + Ahi*Blo + Alo*Bhi   via mfma_f32_16x16x32_bf16.
// Tile: BM = 32*MT (128 or 64), BN = 128, BK = 32.  4 waves (2m x 2n),
// each wave owns (16*MT) x 64 output = MT x 4 subtiles of 16x16.
// LDS chunk swizzle c ^= (row>>1)&3 -> 2-way bank aliasing max (free, m136).
// MODE 1: LN fused on A-load (stats/g/b), epilogue gelu(acc + bias) -> C
// MODE 2: epilogue C += acc + bias  (residual, in place)
// ---------------------------------------------------------------------------
template<int MODE, int MT>
__global__ __launch_bounds__(256, 2)
void mfma_gemm(const float* __restrict__ A, const float* __restrict__ Bw,
               float* __restrict__ C, int K, int ldc,
               const float* __restrict__ stats,
               const float* __restrict__ lng, const float* __restrict__ lnb,
               const float* __restrict__ bias)
{
    constexpr int BM  = 32*MT;
    constexpr int AH  = 0;              // uint offsets into smem
    constexpr int ALO = BM*16;
    constexpr int BH  = 2*BM*16;
    constexpr int BLO = BH + 2048;
    __shared__ uint4 smem4[(2*BM*16 + 4096)/4];
    unsigned int* smem = (unsigned int*)smem4;

    const int tid  = threadIdx.x;
    const int lane = tid & 63, wave = tid >> 6;
    const int wm = wave >> 1, wn = wave & 1;
    const int m0 = blockIdx.x * BM, n0 = blockIdx.y * 128;
    const int lr = lane & 15, lc = lane >> 4;

    float meanv[2], rstdv[2];
    if (MODE == 1){
        #pragma unroll
        for (int it = 0; it < MT/2; ++it){
            const int R = (tid + it*256) >> 2;
            meanv[it] = stats[2*(m0+R)];
            rstdv[it] = stats[2*(m0+R)+1];
        }
    }

    f32x4 acc[MT][4];
    #pragma unroll
    for (int mi=0;mi<MT;mi++)
        #pragma unroll
        for (int ni=0;ni<4;ni++) acc[mi][ni] = (f32x4){0.f,0.f,0.f,0.f};

    for (int k0 = 0; k0 < K; k0 += 32){
        __syncthreads();
        // ---- stage A (BM x 32) as hi/lo bf16, LN fused for MODE 1 ----
        #pragma unroll
        for (int it = 0; it < MT/2; ++it){
            const int pos = tid + it*256;
            const int R = pos >> 2, Cc = pos & 3;
            const float* ap = A + (size_t)(m0 + R)*K + k0 + Cc*8;
            float4 f0 = *(const float4*)ap;
            float4 f1 = *(const float4*)(ap + 4);
            if (MODE == 1){
                const float mn = meanv[it], rs = rstdv[it];
                float4 g0 = *(const float4*)(lng + k0 + Cc*8);
                float4 g1 = *(const float4*)(lng + k0 + Cc*8 + 4);
                float4 q0 = *(const float4*)(lnb + k0 + Cc*8);
                float4 q1 = *(const float4*)(lnb + k0 + Cc*8 + 4);
                f0.x=(f0.x-mn)*rs*g0.x+q0.x; f0.y=(f0.y-mn)*rs*g0.y+q0.y;
                f0.z=(f0.z-mn)*rs*g0.z+q0.z; f0.w=(f0.w-mn)*rs*g0.w+q0.w;
                f1.x=(f1.x-mn)*rs*g1.x+q1.x; f1.y=(f1.y-mn)*rs*g1.y+q1.y;
                f1.z=(f1.z-mn)*rs*g1.z+q1.z; f1.w=(f1.w-mn)*rs*g1.w+q1.w;
            }
            uint4 ph, pl; pack8(f0, f1, ph, pl);
            const int ad = R*16 + ((Cc ^ ((R>>1)&3)) << 2);
            *(uint4*)&smem[AH  + ad] = ph;
            *(uint4*)&smem[ALO + ad] = pl;
        }
        // ---- stage B (128 x 32) as hi/lo bf16 ----
        #pragma unroll
        for (int it = 0; it < 2; ++it){
            const int pos = tid + it*256;
            const int R = pos >> 2, Cc = pos & 3;
            const float* bp = Bw + (size_t)(n0 + R)*K + k0 + Cc*8;
            float4 f0 = *(const float4*)bp;
            float4 f1 = *(const float4*)(bp + 4);
            uint4 ph, pl; pack8(f0, f1, ph, pl);
            const int ad = R*16 + ((Cc ^ ((R>>1)&3)) << 2);
            *(uint4*)&smem[BH  + ad] = ph;
            *(uint4*)&smem[BLO + ad] = pl;
        }
        __syncthreads();
        // ---- fragments: lane holds row (l&15), 8 contiguous k at chunk (l>>4) ----
        bf16x8 ah[MT], al[MT], bh[4], bl[4];
        #pragma unroll
        for (int mi=0; mi<MT; ++mi){
            const int ar = wm*(16*MT) + mi*16 + lr;
            const int ad = ar*16 + ((lc ^ ((ar>>1)&3)) << 2);
            ah[mi] = *reinterpret_cast<const bf16x8*>(&smem[AH  + ad]);
            al[mi] = *reinterpret_cast<const bf16x8*>(&smem[ALO + ad]);
        }
        #pragma unroll
        for (int ni=0; ni<4; ++ni){
            const int br = wn*64 + ni*16 + lr;
            const int ad = br*16 + ((lc ^ ((br>>1)&3)) << 2);
            bh[ni] = *reinterpret_cast<const bf16x8*>(&smem[BH  + ad]);
            bl[ni] = *reinterpret_cast<const bf16x8*>(&smem[BLO + ad]);
        }
        #pragma unroll
        for (int mi=0; mi<MT; ++mi)
            #pragma unroll
            for (int ni=0; ni<4; ++ni){
                acc[mi][ni] = __builtin_amdgcn_mfma_f32_16x16x32_bf16(ah[mi], bh[ni], acc[mi][ni], 0,0,0);
                acc[mi][ni] = __builtin_amdgcn_mfma_f32_16x16x32_bf16(ah[mi], bl[ni], acc[mi][ni], 0,0,0);
                acc[mi][ni] = __builtin_amdgcn_mfma_f32_16x16x32_bf16(al[mi], bh[ni], acc[mi][ni], 0,0,0);
            }
    }
    // ---- epilogue: C/D layout col = lane&15, row = (lane>>4)*4 + q  [m89] ----
    #pragma unroll
    for (int ni=0; ni<4; ++ni){
        const int col = n0 + wn*64 + ni*16 + lr;
        const float bb = bias[col];
        #pragma unroll
        for (int mi=0; mi<MT; ++mi){
            #pragma unroll
            for (int q=0;q<4;q++){
                const int row = m0 + wm*(16*MT) + mi*16 + lc*4 + q;
                const float v = acc[mi][ni][q] + bb;
                float* cp = C + (size_t)row*ldc + col;
                if (MODE == 1) *cp = gelu_exact(v);
                else           *cp += v;
            }
        }
    }
}

// ---------------------------------------------------------------------------
// QKV projection (fp32 NN GEMM): per (n, kh, which) a 4096x128x896 GEMM.
// Store with the head-scramble: h = n*3 + (3t+kh)/1024, pos = (3t+kh)%1024.
// ---------------------------------------------------------------------------
__global__ __launch_bounds__(256)
void qkv_gemm(const float* __restrict__ Z,
              const float* __restrict__ Wq, const float* __restrict__ Wk,
              const float* __restrict__ Wv,
              const float* __restrict__ stats,
              const float* __restrict__ lng, const float* __restrict__ lnb,
              float* __restrict__ qo, float* __restrict__ ko, float* __restrict__ vo)
{
    __shared__ float As[8][64];
    __shared__ float Bs[8][128];
    const int tid = threadIdx.x;
    const int tx = tid & 15, ty = tid >> 4;
    const int m0 = blockIdx.x * 64;
    const int h  = blockIdx.y;
    const int n  = h / KHEADS, kh = h % KHEADS;
    const int which = blockIdx.z;
    const float* Wp = (which==0 ? Wq : which==1 ? Wk : Wv) + (size_t)(kh*NSTREAM + n)*DD*DH;
    float* Op       = (which==0 ? qo : which==1 ? ko : vo);
    const float* Ap = Z + (size_t)n * BT * DD;
    const float* st = stats + (size_t)n * BT * 2;

    const int arow = tid >> 2, ak = (tid & 3) * 2;
    const int bk   = tid >> 5, bn = (tid & 31) * 4;
    const float mean = st[2*(m0+arow)], rstd = st[2*(m0+arow)+1];

    float acc[4][8];
    #pragma unroll
    for (int i=0;i<4;i++)
        #pragma unroll
        for (int j=0;j<8;j++) acc[i][j] = 0.f;

    for (int k0 = 0; k0 < DD; k0 += 8){
        float2 av = *(const float2*)(Ap + (size_t)(m0+arow)*DD + k0 + ak);
        float2 gg = *(const float2*)(lng + k0 + ak);
        float2 bb = *(const float2*)(lnb + k0 + ak);
        av.x = (av.x - mean)*rstd*gg.x + bb.x;
        av.y = (av.y - mean)*rstd*gg.y + bb.y;
        float4 bv = *(const float4*)(Wp + (size_t)(k0+bk)*DH + bn);
        As[ak][arow] = av.x; As[ak+1][arow] = av.y;
        *(float4*)&Bs[bk][bn] = bv;
        __syncthreads();
        #pragma unroll
        for (int kk = 0; kk < 8; ++kk){
            float a[4], b[8];
            *(float4*)(a)   = *(const float4*)&As[kk][ty*4];
            *(float4*)(b)   = *(const float4*)&Bs[kk][tx*8];
            *(float4*)(b+4) = *(const float4*)&Bs[kk][tx*8+4];
            #pragma unroll
            for (int i=0;i<4;i++)
                #pragma unroll
                for (int j=0;j<8;j++) acc[i][j] = fmaf(a[i], b[j], acc[i][j]);
        }
        __syncthreads();
    }
    #pragma unroll
    for (int i=0;i<4;i++){
        const int m = m0 + ty*4 + i;
        const int b = m >> 10, t = m & 1023;
        const int v3 = 3*t + kh;
        const int c = v3 >> 10, p = v3 & 1023;
        float* op = Op + (((size_t)(b*HH + n*KHEADS + c))*TT + p)*DH + tx*8;
        *(float4*)op     = make_float4(acc[i][0],acc[i][1],acc[i][2],acc[i][3]);
        *(float4*)(op+4) = make_float4(acc[i][4],acc[i][5],acc[i][6],acc[i][7]);
    }
}

// ---------------------------------------------------------------------------
// Flash attention, fp32, causal.  BM=64 queries, BN=32 keys, 256 threads.
// Output deposited DIRECTLY into d_out at the final scattered-slot location.
// ---------------------------------------------------------------------------
__global__ __launch_bounds__(256)
void flash_attn(const float* __restrict__ Q, const float* __restrict__ Km,
                const float* __restrict__ Vm, float* __restrict__ Out,
                const int* __restrict__ causal_p)
{
    __shared__ float Qs[64][132];
    __shared__ float KVs[32][130];
    __shared__ float Ps[64][33];
    const int tid = threadIdx.x, tx = tid & 15, ty = tid >> 4;
    const int qt = blockIdx.x, h = blockIdx.y, b = blockIdx.z;
    const int causal = causal_p[0];
    const size_t base = ((size_t)(b*HH + h)) * TT * DH;
    const float* Qp = Q + base + (size_t)qt * 64 * DH;
    const float scl = 0.08838834764831845f;
    const int n = h / KHEADS, c = h % KHEADS;
    const int s_off = (c == 2 ? 3 : c) * DH;

    #pragma unroll
    for (int i=0;i<8;i++){
        int lin = tid + i*256;
        int r = lin >> 5, c4 = (lin & 31) * 4;
        float4 v = *(const float4*)(Qp + r*DH + c4);
        Qs[r][c4]=v.x*scl; Qs[r][c4+1]=v.y*scl; Qs[r][c4+2]=v.z*scl; Qs[r][c4+3]=v.w*scl;
    }
    float acc[4][8];
    float mi[4], li[4];
    #pragma unroll
    for (int i=0;i<4;i++){
        mi[i] = -1e30f; li[i] = 0.f;
        #pragma unroll
        for (int j=0;j<8;j++) acc[i][j] = 0.f;
    }
    const int nkt = causal ? (2*qt + 2) : 32;

    for (int kt = 0; kt < nkt; ++kt){
        const float* Kp = Km + base + (size_t)kt * 32 * DH;
        #pragma unroll
        for (int i=0;i<4;i++){
            int lin = tid + i*256; int r = lin >> 5, c4 = (lin & 31)*4;
            float4 v = *(const float4*)(Kp + r*DH + c4);
            KVs[r][c4]=v.x; KVs[r][c4+1]=v.y; KVs[r][c4+2]=v.z; KVs[r][c4+3]=v.w;
        }
        __syncthreads();

        float s[4][2];
        #pragma unroll
        for (int i=0;i<4;i++){ s[i][0]=0.f; s[i][1]=0.f; }
        #pragma unroll
        for (int d = 0; d < DH; d += 4){
            float qv[4][4], kv[2][4];
            #pragma unroll
            for (int i=0;i<4;i++) *(float4*)qv[i] = *(const float4*)&Qs[ty*4+i][d];
            #pragma unroll
            for (int j=0;j<2;j++){
                *(float2*)(kv[j])   = *(const float2*)&KVs[tx*2+j][d];
                *(float2*)(kv[j]+2) = *(const float2*)&KVs[tx*2+j][d+2];
            }
            #pragma unroll
            for (int i=0;i<4;i++)
                #pragma unroll
                for (int j=0;j<2;j++)
                    #pragma unroll
                    for (int e=0;e<4;e++) s[i][j] = fmaf(qv[i][e], kv[j][e], s[i][j]);
        }
        if (causal && kt >= 2*qt){
            #pragma unroll
            for (int i=0;i<4;i++){
                const int rg = qt*64 + ty*4 + i;
                #pragma unroll
                for (int j=0;j<2;j++){
                    const int cg = kt*32 + tx*2 + j;
                    if (cg > rg) s[i][j] = -1e30f;
                }
            }
        }
        #pragma unroll
        for (int i=0;i<4;i++){
            float mx = fmaxf(s[i][0], s[i][1]);
            #pragma unroll
            for (int off=1; off<16; off<<=1) mx = fmaxf(mx, __shfl_xor(mx, off));
            const float mnew = fmaxf(mi[i], mx);
            const float corr = __expf(mi[i] - mnew);
            const float p0 = __expf(s[i][0] - mnew);
            const float p1 = __expf(s[i][1] - mnew);
            float rs = p0 + p1;
            #pragma unroll
            for (int off=1; off<16; off<<=1) rs += __shfl_xor(rs, off);
            li[i] = li[i]*corr + rs;
            mi[i] = mnew;
            #pragma unroll
            for (int j=0;j<8;j++) acc[i][j] *= corr;
            Ps[ty*4+i][tx*2]   = p0;
            Ps[ty*4+i][tx*2+1] = p1;
        }
        __syncthreads();

        const float* Vp = Vm + base + (size_t)kt * 32 * DH;
        #pragma unroll
        for (int i=0;i<4;i++){
            int lin = tid + i*256; int r = lin >> 5, c4 = (lin & 31)*4;
            float4 v = *(const float4*)(Vp + r*DH + c4);
            KVs[r][c4]=v.x; KVs[r][c4+1]=v.y; KVs[r][c4+2]=v.z; KVs[r][c4+3]=v.w;
        }
        __syncthreads();

        #pragma unroll
        for (int kk = 0; kk < 32; ++kk){
            float pb[4], vv[8];
            #pragma unroll
            for (int i=0;i<4;i++) pb[i] = Ps[ty*4+i][kk];
            #pragma unroll
            for (int j=0;j<4;j++) *(float2*)(vv+2*j) = *(const float2*)&KVs[kk][tx*8+2*j];
            #pragma unroll
            for (int i=0;i<4;i++)
                #pragma unroll
                for (int j=0;j<8;j++) acc[i][j] = fmaf(pb[i], vv[j], acc[i][j]);
        }
        __syncthreads();
    }
    #pragma unroll
    for (int i=0;i<4;i++){
        const float inv = 1.0f / li[i];
        const int p = qt*64 + ty*4 + i;
        float* op = Out + ((size_t)((n*BB + b)*TT + p))*DD + s_off + tx*8;
        *(float4*)op     = make_float4(acc[i][0]*inv,acc[i][1]*inv,acc[i][2]*inv,acc[i][3]*inv);
        *(float4*)(op+4) = make_float4(acc[i][4]*inv,acc[i][5]*inv,acc[i][6]*inv,acc[i][7]*inv);
    }
}

// ---------------------------------------------------------------------------
// Final assembly (in-place on d_out): out = z + (active slot ? out : 0)
// ---------------------------------------------------------------------------
__global__ __launch_bounds__(256)
void assemble(const float* __restrict__ Z, float* __restrict__ out)
{
    const int idx = blockIdx.x * 256 + threadIdx.x;
    const int d4 = idx % 224;
    const size_t loc = (size_t)idx * 4;
    const int s = d4 >> 5;
    float4 v = *(const float4*)(Z + loc);
    if (s == 0 || s == 1 || s == 3){
        const float4 a = *(const float4*)(out + loc);
        v.x += a.x; v.y += a.y; v.z += a.z; v.w += a.w;
    }
    *(float4*)(out + loc) = v;
}

// ---------------------------------------------------------------------------
extern "C" void kernel_launch(void* const* d_in, const int* in_sizes, int n_in,
                              void* d_out, int out_size, void* d_ws, size_t ws_size,
                              hipStream_t stream)
{
    (void)in_sizes; (void)n_in; (void)out_size; (void)ws_size;
    const float* x           = (const float*)d_in[0];
    const float* enc_W       = (const float*)d_in[1];
    const float* stream_bias = (const float*)d_in[2];
    const float* ln_mix_g    = (const float*)d_in[3];
    const float* ln_mix_b    = (const float*)d_in[4];
    const float* W1          = (const float*)d_in[5];
    const float* b1          = (const float*)d_in[6];
    const float* W2          = (const float*)d_in[7];
    const float* b2          = (const float*)d_in[8];
    const float* ln_attn_g   = (const float*)d_in[9];
    const float* ln_attn_b   = (const float*)d_in[10];
    const float* Wq          = (const float*)d_in[11];
    const float* Wk          = (const float*)d_in[12];
    const float* Wv          = (const float*)d_in[13];
    const int*   is_causal   = (const int*)d_in[15];
    float* out = (float*)d_out;

    // ws layout (floats): z | stats | buf{ hidden -> q,k,v }  (~134.3 MB)
    float* z      = (float*)d_ws;
    float* stats  = z + ZSZ;
    float* buf    = stats + NBT*2;
    float* hidden = buf;
    float* qb     = buf;
    float* kb     = qb + QSZ;
    float* vb     = kb + QSZ;

    dim3 blk(256);

    // 1) enc GEMM + stream-bias fan-out (fp32 VALU)
    gemm_nt<0><<<dim3(32, 7), blk, 0, stream>>>(x, enc_W, z, IO, stream_bias);
    // 2) mix-LN stats
    rowstats<<<NBT, blk, 0, stream>>>(z, stats);
    // 3) per-stream MLP via split-bf16 MFMA (LN fused into GEMM1, residual into GEMM2)
    for (int n = 0; n < NSTREAM; ++n){
        mfma_gemm<1,4><<<dim3(32, 28), blk, 0, stream>>>(
            z + (size_t)n*BT*DD, W1, hidden, DD, MIX,
            stats + (size_t)n*BT*2, ln_mix_g, ln_mix_b, b1);
        mfma_gemm<2,2><<<dim3(64, 7), blk, 0, stream>>>(
            hidden, W2, z + (size_t)n*BT*DD, MIX, DD,
            nullptr, nullptr, nullptr, b2);
    }
    // 4) attn-LN stats on z_head
    rowstats<<<NBT, blk, 0, stream>>>(z, stats);
    // 5) QKV projections (fp32, LN fused), scrambled head store
    qkv_gemm<<<dim3(64, HH, 3), blk, 0, stream>>>(z, Wq, Wk, Wv, stats,
                                                  ln_attn_g, ln_attn_b, qb, kb, vb);
    // 6) causal flash attention -> writes straight into d_out (active slots)
    flash_attn<<<dim3(16, HH, BB), blk, 0, stream>>>(qb, kb, vb, out, is_causal);
    // 7) residual + inactive-slot fill, in place on d_out
    assemble<<<ZSZ/4/256, blk, 0, stream>>>(z, out);
}

// Round 4
// 1685.833 us; speedup vs baseline: 1.4926x; 1.4926x over previous
//
#include <hip/hip_runtime.h>
#include <math.h>

// ---- problem constants ----
#define NSTREAM 4
#define KHEADS  3
#define DH      128
#define DD      896        // D = S*DH
#define HH      12         // N*K heads
#define IO      768
#define MIX     3584
#define BB      4
#define TT      1024
#define BT      4096       // B*T
#define NBT     16384      // N*B*T
#define ZSZ     (NSTREAM*BT*DD)   // 14,680,064 floats
#define QSZ     (BB*HH*TT*DH)     // 6,291,456 elements

typedef __attribute__((ext_vector_type(8))) short bf16x8;   // 8 bf16 = 4 VGPR
typedef __attribute__((ext_vector_type(4))) float f32x4;    // MFMA acc
typedef unsigned short u16;

__device__ __forceinline__ float gelu_exact(float x){
    return 0.5f * x * (1.0f + erff(x * 0.70710678118654752f));
}
// fp32 -> bf16 hi (RNE) + bf16 lo (residual)
__device__ __forceinline__ void split1(float x, unsigned &hi, unsigned &lo){
    unsigned u = __float_as_uint(x);
    unsigned r = u + 0x7FFFu + ((u >> 16) & 1u);
    hi = r >> 16;
    float hf = __uint_as_float(r & 0xFFFF0000u);
    float l = x - hf;
    lo = __float_as_uint(l) >> 16;
}
__device__ __forceinline__ u16 bf16r(float x){
    unsigned u = __float_as_uint(x);
    return (u16)((u + 0x7FFFu + ((u >> 16) & 1u)) >> 16);
}
__device__ __forceinline__ void pack8(const float4 &f0, const float4 &f1,
                                      uint4 &ph, uint4 &pl){
    unsigned h0,h1,l0,l1;
    split1(f0.x,h0,l0); split1(f0.y,h1,l1); ph.x = h0|(h1<<16); pl.x = l0|(l1<<16);
    split1(f0.z,h0,l0); split1(f0.w,h1,l1); ph.y = h0|(h1<<16); pl.y = l0|(l1<<16);
    split1(f1.x,h0,l0); split1(f1.y,h1,l1); ph.z = h0|(h1<<16); pl.z = l0|(l1<<16);
    split1(f1.z,h0,l0); split1(f1.w,h1,l1); ph.w = h0|(h1<<16); pl.w = l0|(l1<<16);
}
__device__ __forceinline__ bf16x8 as_bf(uint4 v){
    union{uint4 u; bf16x8 b;} x; x.u = v; return x.b;
}

// ---------------------------------------------------------------------------
// Row statistics for LayerNorm fusion.
// ---------------------------------------------------------------------------
__global__ __launch_bounds__(256)
void rowstats(const float* __restrict__ X, float* __restrict__ st)
{
    const int r = blockIdx.x;
    const float* xp = X + (size_t)r * DD;
    const int tid = threadIdx.x;
    float s = 0.f, sq = 0.f;
    if (tid < 224){
        float4 v = *(const float4*)(xp + tid*4);
        s  = v.x + v.y + v.z + v.w;
        sq = v.x*v.x + v.y*v.y + v.z*v.z + v.w*v.w;
    }
    #pragma unroll
    for (int off = 32; off >= 1; off >>= 1){
        s  += __shfl_down(s,  off);
        sq += __shfl_down(sq, off);
    }
    __shared__ float ps[4], pq[4];
    if ((tid & 63) == 0){ ps[tid>>6] = s; pq[tid>>6] = sq; }
    __syncthreads();
    if (tid == 0){
        s  = ps[0]+ps[1]+ps[2]+ps[3];
        sq = pq[0]+pq[1]+pq[2]+pq[3];
        float mean = s * (1.0f/DD);
        float var  = sq * (1.0f/DD) - mean*mean;
        st[2*r]   = mean;
        st[2*r+1] = rsqrtf(var + 1e-5f);
    }
}

// ---------------------------------------------------------------------------
// fp32 NT GEMM (VALU) for the encoder; epilogue fans out + stream_bias.
// ---------------------------------------------------------------------------
__global__ __launch_bounds__(256)
void gemm_enc(const float* __restrict__ A, const float* __restrict__ Bw,
              float* __restrict__ C, int K, const float* __restrict__ bias)
{
    __shared__ float As[8][128];
    __shared__ float Bs[8][128];
    const int tid = threadIdx.x;
    const int tx = tid & 15, ty = tid >> 4;
    const int m0 = blockIdx.x * 128, n0 = blockIdx.y * 128;
    const int lrow = tid >> 1;
    const int lk   = (tid & 1) * 4;
    const float* Ap = A  + (size_t)(m0 + lrow) * K + lk;
    const float* Bp = Bw + (size_t)(n0 + lrow) * K + lk;

    float acc[8][8];
    #pragma unroll
    for (int i=0;i<8;i++)
        #pragma unroll
        for (int j=0;j<8;j++) acc[i][j] = 0.f;

    for (int k0 = 0; k0 < K; k0 += 8){
        float4 av = *(const float4*)(Ap + k0);
        float4 bv = *(const float4*)(Bp + k0);
        As[lk+0][lrow]=av.x; As[lk+1][lrow]=av.y; As[lk+2][lrow]=av.z; As[lk+3][lrow]=av.w;
        Bs[lk+0][lrow]=bv.x; Bs[lk+1][lrow]=bv.y; Bs[lk+2][lrow]=bv.z; Bs[lk+3][lrow]=bv.w;
        __syncthreads();
        #pragma unroll
        for (int kk = 0; kk < 8; ++kk){
            float a[8], b[8];
            *(float4*)(a)   = *(const float4*)&As[kk][ty*8];
            *(float4*)(a+4) = *(const float4*)&As[kk][ty*8+4];
            *(float4*)(b)   = *(const float4*)&Bs[kk][tx*8];
            *(float4*)(b+4) = *(const float4*)&Bs[kk][tx*8+4];
            #pragma unroll
            for (int i=0;i<8;i++)
                #pragma unroll
                for (int j=0;j<8;j++) acc[i][j] = fmaf(a[i], b[j], acc[i][j]);
        }
        __syncthreads();
    }
    const int rm = m0 + ty*8, rn = n0 + tx*8;
    #pragma unroll
    for (int nn = 0; nn < NSTREAM; ++nn){
        float4 s0 = *(const float4*)(bias + nn*DD + rn);
        float4 s1 = *(const float4*)(bias + nn*DD + rn + 4);
        #pragma unroll
        for (int i=0;i<8;i++){
            float* cp = C + (size_t)(nn*BT + rm + i)*DD + rn;
            float4 o0, o1;
            o0.x=acc[i][0]+s0.x; o0.y=acc[i][1]+s0.y; o0.z=acc[i][2]+s0.z; o0.w=acc[i][3]+s0.w;
            o1.x=acc[i][4]+s1.x; o1.y=acc[i][5]+s1.y; o1.z=acc[i][6]+s1.z; o1.w=acc[i][7]+s1.w;
            *(float4*)cp = o0; *(float4*)(cp+4) = o1;
        }
    }
}

// ---------------------------------------------------------------------------
// bf16x3 split-MFMA NT GEMM for the MLP (PROVEN in round 3).
// MODE 1: LN fused on A-load, epilogue gelu(acc+bias) -> C
// MODE 2: epilogue C += acc + bias (residual, in place)
// ---------------------------------------------------------------------------
template<int MODE, int MT>
__global__ __launch_bounds__(256, 2)
void mfma_gemm(const float* __restrict__ A, const float* __restrict__ Bw,
               float* __restrict__ C, int K, int ldc,
               const float* __restrict__ stats,
               const float* __restrict__ lng, const float* __restrict__ lnb,
               const float* __restrict__ bias)
{
    constexpr int BM  = 32*MT;
    constexpr int AH  = 0;
    constexpr int ALO = BM*16;
    constexpr int BH  = 2*BM*16;
    constexpr int BLO = BH + 2048;
    __shared__ uint4 smem4[(2*BM*16 + 4096)/4];
    unsigned int* smem = (unsigned int*)smem4;

    const int tid  = threadIdx.x;
    const int lane = tid & 63, wave = tid >> 6;
    const int wm = wave >> 1, wn = wave & 1;
    const int m0 = blockIdx.x * BM, n0 = blockIdx.y * 128;
    const int lr = lane & 15, lc = lane >> 4;

    float meanv[2], rstdv[2];
    if (MODE == 1){
        #pragma unroll
        for (int it = 0; it < MT/2; ++it){
            const int R = (tid + it*256) >> 2;
            meanv[it] = stats[2*(m0+R)];
            rstdv[it] = stats[2*(m0+R)+1];
        }
    }
    f32x4 acc[MT][4];
    #pragma unroll
    for (int mi=0;mi<MT;mi++)
        #pragma unroll
        for (int ni=0;ni<4;ni++) acc[mi][ni] = (f32x4){0.f,0.f,0.f,0.f};

    for (int k0 = 0; k0 < K; k0 += 32){
        __syncthreads();
        #pragma unroll
        for (int it = 0; it < MT/2; ++it){
            const int pos = tid + it*256;
            const int R = pos >> 2, Cc = pos & 3;
            const float* ap = A + (size_t)(m0 + R)*K + k0 + Cc*8;
            float4 f0 = *(const float4*)ap;
            float4 f1 = *(const float4*)(ap + 4);
            if (MODE == 1){
                const float mn = meanv[it], rs = rstdv[it];
                float4 g0 = *(const float4*)(lng + k0 + Cc*8);
                float4 g1 = *(const float4*)(lng + k0 + Cc*8 + 4);
                float4 q0 = *(const float4*)(lnb + k0 + Cc*8);
                float4 q1 = *(const float4*)(lnb + k0 + Cc*8 + 4);
                f0.x=(f0.x-mn)*rs*g0.x+q0.x; f0.y=(f0.y-mn)*rs*g0.y+q0.y;
                f0.z=(f0.z-mn)*rs*g0.z+q0.z; f0.w=(f0.w-mn)*rs*g0.w+q0.w;
                f1.x=(f1.x-mn)*rs*g1.x+q1.x; f1.y=(f1.y-mn)*rs*g1.y+q1.y;
                f1.z=(f1.z-mn)*rs*g1.z+q1.z; f1.w=(f1.w-mn)*rs*g1.w+q1.w;
            }
            uint4 ph, pl; pack8(f0, f1, ph, pl);
            const int ad = R*16 + ((Cc ^ ((R>>1)&3)) << 2);
            *(uint4*)&smem[AH  + ad] = ph;
            *(uint4*)&smem[ALO + ad] = pl;
        }
        #pragma unroll
        for (int it = 0; it < 2; ++it){
            const int pos = tid + it*256;
            const int R = pos >> 2, Cc = pos & 3;
            const float* bp = Bw + (size_t)(n0 + R)*K + k0 + Cc*8;
            float4 f0 = *(const float4*)bp;
            float4 f1 = *(const float4*)(bp + 4);
            uint4 ph, pl; pack8(f0, f1, ph, pl);
            const int ad = R*16 + ((Cc ^ ((R>>1)&3)) << 2);
            *(uint4*)&smem[BH  + ad] = ph;
            *(uint4*)&smem[BLO + ad] = pl;
        }
        __syncthreads();
        bf16x8 ah[MT], al[MT], bh[4], bl[4];
        #pragma unroll
        for (int mi=0; mi<MT; ++mi){
            const int ar = wm*(16*MT) + mi*16 + lr;
            const int ad = ar*16 + ((lc ^ ((ar>>1)&3)) << 2);
            ah[mi] = *reinterpret_cast<const bf16x8*>(&smem[AH  + ad]);
            al[mi] = *reinterpret_cast<const bf16x8*>(&smem[ALO + ad]);
        }
        #pragma unroll
        for (int ni=0; ni<4; ++ni){
            const int br = wn*64 + ni*16 + lr;
            const int ad = br*16 + ((lc ^ ((br>>1)&3)) << 2);
            bh[ni] = *reinterpret_cast<const bf16x8*>(&smem[BH  + ad]);
            bl[ni] = *reinterpret_cast<const bf16x8*>(&smem[BLO + ad]);
        }
        #pragma unroll
        for (int mi=0; mi<MT; ++mi)
            #pragma unroll
            for (int ni=0; ni<4; ++ni){
                acc[mi][ni] = __builtin_amdgcn_mfma_f32_16x16x32_bf16(ah[mi], bh[ni], acc[mi][ni], 0,0,0);
                acc[mi][ni] = __builtin_amdgcn_mfma_f32_16x16x32_bf16(ah[mi], bl[ni], acc[mi][ni], 0,0,0);
                acc[mi][ni] = __builtin_amdgcn_mfma_f32_16x16x32_bf16(al[mi], bh[ni], acc[mi][ni], 0,0,0);
            }
    }
    #pragma unroll
    for (int ni=0; ni<4; ++ni){
        const int col = n0 + wn*64 + ni*16 + lr;
        const float bb = bias[col];
        #pragma unroll
        for (int mi=0; mi<MT; ++mi){
            #pragma unroll
            for (int q=0;q<4;q++){
                const int row = m0 + wm*(16*MT) + mi*16 + lc*4 + q;
                const float v = acc[mi][ni][q] + bb;
                float* cp = C + (size_t)row*ldc + col;
                if (MODE == 1) *cp = gelu_exact(v);
                else           *cp += v;
            }
        }
    }
}

// ---------------------------------------------------------------------------
// Weight transpose+split: W[12][896][128] -> wt_hi/lo[3][12][128][896] bf16.
// grid (12, 28, 3), block 256.
// ---------------------------------------------------------------------------
__global__ __launch_bounds__(256)
void wt_split(const float* __restrict__ Wq, const float* __restrict__ Wk,
              const float* __restrict__ Wv, u16* __restrict__ wh, u16* __restrict__ wl)
{
    __shared__ float ftile[32][132];
    const int tid = threadIdx.x;
    const int widx = blockIdx.x, k0 = blockIdx.y*32, which = blockIdx.z;
    const float* W = (which==0 ? Wq : which==1 ? Wk : Wv) + (size_t)widx*DD*DH;
    #pragma unroll
    for (int it=0; it<4; ++it){
        const int pos = tid + it*256;
        const int r = pos >> 5, c4 = (pos & 31)*4;
        float4 v = *(const float4*)(W + (size_t)(k0+r)*DH + c4);
        *(float4*)&ftile[r][c4] = v;
    }
    __syncthreads();
    const int ct = tid >> 1, kseg = (tid & 1)*16;
    unsigned hi[8], lo[8];   // packed pairs
    #pragma unroll
    for (int jj=0; jj<8; ++jj){
        unsigned h0,l0,h1,l1;
        split1(ftile[kseg+2*jj  ][ct], h0, l0);
        split1(ftile[kseg+2*jj+1][ct], h1, l1);
        hi[jj] = h0 | (h1<<16);  lo[jj] = l0 | (l1<<16);
    }
    u16* op = wh + ((size_t)((which*12+widx)*128 + ct))*DD + k0 + kseg;
    *(uint4*)op     = make_uint4(hi[0],hi[1],hi[2],hi[3]);
    *(uint4*)(op+8) = make_uint4(hi[4],hi[5],hi[6],hi[7]);
    u16* ol = wl + ((size_t)((which*12+widx)*128 + ct))*DD + k0 + kseg;
    *(uint4*)ol     = make_uint4(lo[0],lo[1],lo[2],lo[3]);
    *(uint4*)(ol+8) = make_uint4(lo[4],lo[5],lo[6],lo[7]);
}

// ---------------------------------------------------------------------------
// QKV projection, split-bf16 MFMA NT GEMM (fp32-accurate), outputs bf16.
// grid (32, 36): by = which*12 + widx, widx = kh*4 + n.
// A = z (stream n, attn-LN fused+split on load), B = wt (pre-split).
// Epilogue: head-scramble store h=n*3+(3t+kh)/1024, p=(3t+kh)%1024, bf16.
// ---------------------------------------------------------------------------
__global__ __launch_bounds__(256, 2)
void qkv_mfma(const float* __restrict__ Z,
              const u16* __restrict__ wh, const u16* __restrict__ wl,
              const float* __restrict__ stats,
              const float* __restrict__ lng, const float* __restrict__ lnb,
              u16* __restrict__ qo, u16* __restrict__ ko, u16* __restrict__ vo)
{
    constexpr int AH = 0, ALO = 2048, BH = 4096, BLO = 6144;
    __shared__ uint4 smem4[8192/4];
    unsigned int* smem = (unsigned int*)smem4;

    const int tid  = threadIdx.x;
    const int lane = tid & 63, wave = tid >> 6;
    const int wm = wave >> 1, wn = wave & 1;
    const int lr = lane & 15, lc = lane >> 4;
    const int m0 = blockIdx.x * 128;
    const int comb = blockIdx.y;
    const int which = comb / 12, widx = comb % 12;
    const int kh = widx >> 2, n = widx & 3;
    const float* Ap = Z + (size_t)n * BT * DD;
    const float* st = stats + (size_t)n * BT * 2;
    const u16* Bh = wh + (size_t)comb * 128 * DD;
    const u16* Bl = wl + (size_t)comb * 128 * DD;
    u16* Op = (which==0 ? qo : which==1 ? ko : vo);

    float meanv[2], rstdv[2];
    #pragma unroll
    for (int it = 0; it < 2; ++it){
        const int R = (tid + it*256) >> 2;
        meanv[it] = st[2*(m0+R)];
        rstdv[it] = st[2*(m0+R)+1];
    }
    f32x4 acc[4][4];
    #pragma unroll
    for (int mi=0;mi<4;mi++)
        #pragma unroll
        for (int ni=0;ni<4;ni++) acc[mi][ni] = (f32x4){0.f,0.f,0.f,0.f};

    for (int k0 = 0; k0 < DD; k0 += 32){
        __syncthreads();
        #pragma unroll
        for (int it = 0; it < 2; ++it){
            const int pos = tid + it*256;
            const int R = pos >> 2, Cc = pos & 3;
            const float* ap = Ap + (size_t)(m0 + R)*DD + k0 + Cc*8;
            float4 f0 = *(const float4*)ap;
            float4 f1 = *(const float4*)(ap + 4);
            const float mn = meanv[it], rs = rstdv[it];
            float4 g0 = *(const float4*)(lng + k0 + Cc*8);
            float4 g1 = *(const float4*)(lng + k0 + Cc*8 + 4);
            float4 q0 = *(const float4*)(lnb + k0 + Cc*8);
            float4 q1 = *(const float4*)(lnb + k0 + Cc*8 + 4);
            f0.x=(f0.x-mn)*rs*g0.x+q0.x; f0.y=(f0.y-mn)*rs*g0.y+q0.y;
            f0.z=(f0.z-mn)*rs*g0.z+q0.z; f0.w=(f0.w-mn)*rs*g0.w+q0.w;
            f1.x=(f1.x-mn)*rs*g1.x+q1.x; f1.y=(f1.y-mn)*rs*g1.y+q1.y;
            f1.z=(f1.z-mn)*rs*g1.z+q1.z; f1.w=(f1.w-mn)*rs*g1.w+q1.w;
            uint4 ph, pl; pack8(f0, f1, ph, pl);
            const int ad = R*16 + ((Cc ^ ((R>>1)&3)) << 2);
            *(uint4*)&smem[AH  + ad] = ph;
            *(uint4*)&smem[ALO + ad] = pl;
        }
        #pragma unroll
        for (int it = 0; it < 2; ++it){
            const int pos = tid + it*256;
            const int R = pos >> 2, Cc = pos & 3;
            const int ad = R*16 + ((Cc ^ ((R>>1)&3)) << 2);
            *(uint4*)&smem[BH  + ad] = *(const uint4*)(Bh + (size_t)R*DD + k0 + Cc*8);
            *(uint4*)&smem[BLO + ad] = *(const uint4*)(Bl + (size_t)R*DD + k0 + Cc*8);
        }
        __syncthreads();
        bf16x8 ah[4], al[4], bh[4], bl[4];
        #pragma unroll
        for (int mi=0; mi<4; ++mi){
            const int ar = wm*64 + mi*16 + lr;
            const int ad = ar*16 + ((lc ^ ((ar>>1)&3)) << 2);
            ah[mi] = *reinterpret_cast<const bf16x8*>(&smem[AH  + ad]);
            al[mi] = *reinterpret_cast<const bf16x8*>(&smem[ALO + ad]);
        }
        #pragma unroll
        for (int ni=0; ni<4; ++ni){
            const int br = wn*64 + ni*16 + lr;
            const int ad = br*16 + ((lc ^ ((br>>1)&3)) << 2);
            bh[ni] = *reinterpret_cast<const bf16x8*>(&smem[BH  + ad]);
            bl[ni] = *reinterpret_cast<const bf16x8*>(&smem[BLO + ad]);
        }
        #pragma unroll
        for (int mi=0; mi<4; ++mi)
            #pragma unroll
            for (int ni=0; ni<4; ++ni){
                acc[mi][ni] = __builtin_amdgcn_mfma_f32_16x16x32_bf16(ah[mi], bh[ni], acc[mi][ni], 0,0,0);
                acc[mi][ni] = __builtin_amdgcn_mfma_f32_16x16x32_bf16(ah[mi], bl[ni], acc[mi][ni], 0,0,0);
                acc[mi][ni] = __builtin_amdgcn_mfma_f32_16x16x32_bf16(al[mi], bh[ni], acc[mi][ni], 0,0,0);
            }
    }
    #pragma unroll
    for (int mi=0; mi<4; ++mi){
        #pragma unroll
        for (int q=0;q<4;q++){
            const int m = m0 + wm*64 + mi*16 + lc*4 + q;
            const int b = m >> 10, t = m & 1023;
            const int v3 = 3*t + kh;
            const int c = v3 >> 10, p = v3 & 1023;
            u16* op = Op + ((size_t)((b*HH + n*KHEADS + c)*TT + p))*DH;
            #pragma unroll
            for (int ni=0; ni<4; ++ni){
                const int col = wn*64 + ni*16 + lr;
                op[col] = bf16r(acc[mi][ni][q]);
            }
        }
    }
}

// ---------------------------------------------------------------------------
// Flash attention, bf16 MFMA.  4 waves x 16 q-rows = 64 q / block, KVBLK=64.
// K staged [key][dh], V transpose-staged [dh][key], both XOR-swizzled.
// Online softmax wave-parallel via shfl_xor over the 16-lane row groups.
// Writes fp32 straight into d_out at the scattered active-slot location.
// ---------------------------------------------------------------------------
__global__ __launch_bounds__(256)
void flash_mfma(const u16* __restrict__ qb, const u16* __restrict__ kb,
                const u16* __restrict__ vb, float* __restrict__ Out,
                const int* __restrict__ causal_p)
{
    __shared__ u16 lds[8192 + 8192 + 4608];
    u16* Ks = lds;
    u16* Vt = lds + 8192;
    u16* Pl = lds + 16384;
    const int tid = threadIdx.x, lane = tid & 63, wv = tid >> 6;
    const int lr = lane & 15, lc = lane >> 4;
    const int qt = (int)gridDim.x - 1 - (int)blockIdx.x;   // heavy tiles first
    const int h = blockIdx.y, b = blockIdx.z;
    const int causal = causal_p[0];
    const int n = h / KHEADS, c = h % KHEADS;
    const int s_off = (c == 2 ? 3 : c) * DH;
    const size_t base = (size_t)(b*HH + h) * TT * DH;
    const float scl = 0.08838834764831845f;

    uint4 qf[4];
    const int qrow = qt*64 + wv*16 + lr;
    #pragma unroll
    for (int kc=0; kc<4; ++kc)
        qf[kc] = *(const uint4*)(qb + base + (size_t)qrow*DH + kc*32 + lc*8);

    f32x4 o[8];
    #pragma unroll
    for (int i=0;i<8;i++) o[i] = (f32x4){0.f,0.f,0.f,0.f};
    float mi[4], li[4];
    #pragma unroll
    for (int j=0;j<4;j++){ mi[j] = -1e30f; li[j] = 0.f; }

    const int nkt = causal ? (qt + 1) : 16;
    for (int kt = 0; kt < nkt; ++kt){
        __syncthreads();
        // ---- stage K tile [64][128] ----
        #pragma unroll
        for (int it=0; it<4; ++it){
            const int pos = tid + it*256;
            const int key = pos >> 4, sc = pos & 15;
            uint4 v = *(const uint4*)(kb + base + (size_t)(kt*64+key)*DH + sc*8);
            const int kc = sc >> 2, cc = sc & 3;
            const int word = key*64 + ((kc ^ (key&3))<<4) + ((cc ^ ((key>>2)&3))<<2);
            *(uint4*)(Ks + word*2) = v;
        }
        // ---- stage V tile transposed [128][64] ----
        #pragma unroll
        for (int it=0; it<4; ++it){
            const int pos = tid + it*256;
            const int sc = pos >> 6, key = pos & 63;
            uint4 v = *(const uint4*)(vb + base + (size_t)(kt*64+key)*DH + sc*8);
            const u16* e = (const u16*)&v;
            const int kcv = key>>5, cv = (key>>3)&3, w_ = (key>>1)&3, half = key&1;
            #pragma unroll
            for (int j=0;j<8;++j){
                const int dh = sc*8 + j;
                const int word = dh*32 + ((kcv ^ (dh&1))<<4) + ((cv ^ ((dh>>1)&3))<<2) + w_;
                Vt[word*2 + half] = e[j];
            }
        }
        __syncthreads();
        // ---- QK^T ----
        f32x4 s[4];
        #pragma unroll
        for (int nk=0;nk<4;nk++) s[nk] = (f32x4){0.f,0.f,0.f,0.f};
        #pragma unroll
        for (int kc=0; kc<4; ++kc){
            #pragma unroll
            for (int nk=0; nk<4; ++nk){
                const int key = nk*16 + lr;
                const int word = key*64 + ((kc ^ (key&3))<<4) + ((lc ^ ((key>>2)&3))<<2);
                uint4 kf = *(const uint4*)(Ks + word*2);
                s[nk] = __builtin_amdgcn_mfma_f32_16x16x32_bf16(as_bf(qf[kc]), as_bf(kf), s[nk], 0,0,0);
            }
        }
        #pragma unroll
        for (int nk=0;nk<4;nk++){
            s[nk][0]*=scl; s[nk][1]*=scl; s[nk][2]*=scl; s[nk][3]*=scl;
        }
        if (causal && kt == qt){
            #pragma unroll
            for (int nk=0;nk<4;nk++){
                const int keyg = kt*64 + nk*16 + lr;
                #pragma unroll
                for (int j=0;j<4;j++){
                    const int qg = qt*64 + wv*16 + lc*4 + j;
                    if (keyg > qg) s[nk][j] = -1e30f;
                }
            }
        }
        // ---- online softmax (rows = lc*4+j, distributed over 16 lr lanes) ----
        #pragma unroll
        for (int j=0;j<4;j++){
            float mx = fmaxf(fmaxf(s[0][j], s[1][j]), fmaxf(s[2][j], s[3][j]));
            #pragma unroll
            for (int off=1; off<16; off<<=1) mx = fmaxf(mx, __shfl_xor(mx, off));
            const float mnew = fmaxf(mi[j], mx);
            const float corr = __expf(mi[j] - mnew);
            float p0 = __expf(s[0][j]-mnew), p1 = __expf(s[1][j]-mnew);
            float p2 = __expf(s[2][j]-mnew), p3 = __expf(s[3][j]-mnew);
            float rs = p0+p1+p2+p3;
            #pragma unroll
            for (int off=1; off<16; off<<=1) rs += __shfl_xor(rs, off);
            li[j] = li[j]*corr + rs;
            mi[j] = mnew;
            #pragma unroll
            for (int ni=0;ni<8;ni++) o[ni][j] *= corr;
            const int prow = lc*4 + j;
            u16* pw = Pl + wv*1152 + prow*72;
            pw[lr]      = bf16r(p0);
            pw[16 + lr] = bf16r(p1);
            pw[32 + lr] = bf16r(p2);
            pw[48 + lr] = bf16r(p3);
        }
        // ---- PV ----
        uint4 pf[2];
        #pragma unroll
        for (int kc2=0; kc2<2; ++kc2)
            pf[kc2] = *(const uint4*)(Pl + wv*1152 + lr*72 + kc2*32 + lc*8);
        #pragma unroll
        for (int kc2=0; kc2<2; ++kc2){
            #pragma unroll
            for (int ni=0; ni<8; ++ni){
                const int dh = ni*16 + lr;
                const int word = dh*32 + ((kc2 ^ (dh&1))<<4) + ((lc ^ ((dh>>1)&3))<<2);
                uint4 vf = *(const uint4*)(Vt + word*2);
                o[ni] = __builtin_amdgcn_mfma_f32_16x16x32_bf16(as_bf(pf[kc2]), as_bf(vf), o[ni], 0,0,0);
            }
        }
    }
    // ---- epilogue ----
    float inv[4];
    #pragma unroll
    for (int j=0;j<4;j++) inv[j] = 1.0f / li[j];
    #pragma unroll
    for (int j=0;j<4;j++){
        const int p = qt*64 + wv*16 + lc*4 + j;
        float* op = Out + ((size_t)((n*BB + b)*TT + p))*DD + s_off;
        #pragma unroll
        for (int ni=0; ni<8; ++ni)
            op[ni*16 + lr] = o[ni][j] * inv[j];
    }
}

// ---------------------------------------------------------------------------
// Final assembly (in-place on d_out): out = z + (active slot ? out : 0)
// ---------------------------------------------------------------------------
__global__ __launch_bounds__(256)
void assemble(const float* __restrict__ Z, float* __restrict__ out)
{
    const int idx = blockIdx.x * 256 + threadIdx.x;
    const int d4 = idx % 224;
    const size_t loc = (size_t)idx * 4;
    const int s = d4 >> 5;
    float4 v = *(const float4*)(Z + loc);
    if (s == 0 || s == 1 || s == 3){
        const float4 a = *(const float4*)(out + loc);
        v.x += a.x; v.y += a.y; v.z += a.z; v.w += a.w;
    }
    *(float4*)(out + loc) = v;
}

// ---------------------------------------------------------------------------
extern "C" void kernel_launch(void* const* d_in, const int* in_sizes, int n_in,
                              void* d_out, int out_size, void* d_ws, size_t ws_size,
                              hipStream_t stream)
{
    (void)in_sizes; (void)n_in; (void)out_size; (void)ws_size;
    const float* x           = (const float*)d_in[0];
    const float* enc_W       = (const float*)d_in[1];
    const float* stream_bias = (const float*)d_in[2];
    const float* ln_mix_g    = (const float*)d_in[3];
    const float* ln_mix_b    = (const float*)d_in[4];
    const float* W1          = (const float*)d_in[5];
    const float* b1          = (const float*)d_in[6];
    const float* W2          = (const float*)d_in[7];
    const float* b2          = (const float*)d_in[8];
    const float* ln_attn_g   = (const float*)d_in[9];
    const float* ln_attn_b   = (const float*)d_in[10];
    const float* Wq          = (const float*)d_in[11];
    const float* Wk          = (const float*)d_in[12];
    const float* Wv          = (const float*)d_in[13];
    const int*   is_causal   = (const int*)d_in[15];
    float* out = (float*)d_out;

    // ws (floats): z(14.68M) | stats(32K) | buf: max(hidden 14.68M f32,
    //   qkv bf16 3*QSZ=18.87M u16 = 9.44M f32) | wt hi+lo (8.26M u16 = 4.13M f32)
    // total = 33.53M floats = 134.1 MB  (<= round-3's proven 134.3 MB)
    float* z      = (float*)d_ws;
    float* stats  = z + ZSZ;
    float* buf    = stats + NBT*2;
    float* hidden = buf;
    u16*   qbuf   = (u16*)buf;
    u16*   kbuf   = qbuf + QSZ;
    u16*   vbuf   = kbuf + QSZ;
    u16*   wth    = (u16*)(buf + ZSZ);
    u16*   wtl    = wth + 3*HH*DH*DD;

    dim3 blk(256);

    // 1) enc GEMM + stream-bias fan-out (fp32 VALU)
    gemm_enc<<<dim3(32, 7), blk, 0, stream>>>(x, enc_W, z, IO, stream_bias);
    // 2) weight transpose+split for QKV (independent)
    wt_split<<<dim3(12, 28, 3), blk, 0, stream>>>(Wq, Wk, Wv, wth, wtl);
    // 3) mix-LN stats
    rowstats<<<NBT, blk, 0, stream>>>(z, stats);
    // 4) per-stream MLP (split-bf16 MFMA; LN fused in GEMM1, residual in GEMM2)
    for (int nn = 0; nn < NSTREAM; ++nn){
        mfma_gemm<1,4><<<dim3(32, 28), blk, 0, stream>>>(
            z + (size_t)nn*BT*DD, W1, hidden, DD, MIX,
            stats + (size_t)nn*BT*2, ln_mix_g, ln_mix_b, b1);
        mfma_gemm<2,2><<<dim3(64, 7), blk, 0, stream>>>(
            hidden, W2, z + (size_t)nn*BT*DD, MIX, DD,
            nullptr, nullptr, nullptr, b2);
    }
    // 5) attn-LN stats
    rowstats<<<NBT, blk, 0, stream>>>(z, stats);
    // 6) QKV projections (split-bf16 MFMA, LN fused), scrambled bf16 store
    qkv_mfma<<<dim3(32, 36), blk, 0, stream>>>(z, wth, wtl, stats,
                                               ln_attn_g, ln_attn_b,
                                               qbuf, kbuf, vbuf);
    // 7) causal flash attention (bf16 MFMA) -> writes into d_out active slots
    flash_mfma<<<dim3(16, HH, BB), blk, 0, stream>>>(qbuf, kbuf, vbuf, out, is_causal);
    // 8) residual + inactive-slot fill, in place on d_out
    assemble<<<ZSZ/4/256, blk, 0, stream>>>(z, out);
}

// Round 7
// 1675.855 us; speedup vs baseline: 1.5015x; 1.0060x over previous
//
#include <hip/hip_runtime.h>
#include <math.h>

// ---- problem constants ----
#define NSTREAM 4
#define KHEADS  3
#define DH      128
#define DD      896        // D = S*DH
#define HH      12         // N*K heads
#define IO      768
#define MIX     3584
#define BB      4
#define TT      1024
#define BT      4096       // B*T
#define NBT     16384      // N*B*T
#define ZSZ     (NSTREAM*BT*DD)   // 14,680,064 floats
#define QSZ     (BB*HH*TT*DH)     // 6,291,456 elements

typedef __attribute__((ext_vector_type(8))) short bf16x8;
typedef __attribute__((ext_vector_type(4))) float f32x4;
typedef unsigned short u16;

__device__ __forceinline__ float gelu_exact(float x){
    return 0.5f * x * (1.0f + erff(x * 0.70710678118654752f));
}
__device__ __forceinline__ void split1(float x, unsigned &hi, unsigned &lo){
    unsigned u = __float_as_uint(x);
    unsigned r = u + 0x7FFFu + ((u >> 16) & 1u);
    hi = r >> 16;
    float hf = __uint_as_float(r & 0xFFFF0000u);
    float l = x - hf;
    lo = __float_as_uint(l) >> 16;
}
__device__ __forceinline__ u16 bf16r(float x){
    unsigned u = __float_as_uint(x);
    return (u16)((u + 0x7FFFu + ((u >> 16) & 1u)) >> 16);
}
__device__ __forceinline__ void pack8(const float4 &f0, const float4 &f1,
                                      uint4 &ph, uint4 &pl){
    unsigned h0,h1,l0,l1;
    split1(f0.x,h0,l0); split1(f0.y,h1,l1); ph.x = h0|(h1<<16); pl.x = l0|(l1<<16);
    split1(f0.z,h0,l0); split1(f0.w,h1,l1); ph.y = h0|(h1<<16); pl.y = l0|(l1<<16);
    split1(f1.x,h0,l0); split1(f1.y,h1,l1); ph.z = h0|(h1<<16); pl.z = l0|(l1<<16);
    split1(f1.z,h0,l0); split1(f1.w,h1,l1); ph.w = h0|(h1<<16); pl.w = l0|(l1<<16);
}
__device__ __forceinline__ bf16x8 as_bf(uint4 v){
    union{uint4 u; bf16x8 b;} x; x.u = v; return x.b;
}

// ---------------------------------------------------------------------------
// Generic fp32 -> (hi,lo) bf16 pre-split.  One float4x2 per thread.
// ---------------------------------------------------------------------------
__global__ __launch_bounds__(256)
void split_pair(const float* __restrict__ X, u16* __restrict__ H,
                u16* __restrict__ L, int n8)
{
    const int i = blockIdx.x*256 + threadIdx.x;
    if (i >= n8) return;
    float4 f0 = *(const float4*)(X + (size_t)i*8);
    float4 f1 = *(const float4*)(X + (size_t)i*8 + 4);
    uint4 ph, pl; pack8(f0, f1, ph, pl);
    *(uint4*)(H + (size_t)i*8) = ph;
    *(uint4*)(L + (size_t)i*8) = pl;
}

// ---------------------------------------------------------------------------
// Fused rowstats + LayerNorm + split.  One block per 896-row.
// Stats reduction identical to the round-3/4 rowstats (bit-identical stats).
// ---------------------------------------------------------------------------
__global__ __launch_bounds__(256)
void ln_split(const float* __restrict__ Z, const float* __restrict__ g,
              const float* __restrict__ bt, u16* __restrict__ H, u16* __restrict__ L)
{
    const int r = blockIdx.x;
    const float* xp = Z + (size_t)r * DD;
    const int tid = threadIdx.x;
    float4 v = make_float4(0.f,0.f,0.f,0.f);
    float s = 0.f, sq = 0.f;
    if (tid < 224){
        v = *(const float4*)(xp + tid*4);
        s  = v.x + v.y + v.z + v.w;
        sq = v.x*v.x + v.y*v.y + v.z*v.z + v.w*v.w;
    }
    #pragma unroll
    for (int off = 32; off >= 1; off >>= 1){
        s  += __shfl_down(s,  off);
        sq += __shfl_down(sq, off);
    }
    __shared__ float ps[4], pq[4], sm, sv;
    if ((tid & 63) == 0){ ps[tid>>6] = s; pq[tid>>6] = sq; }
    __syncthreads();
    if (tid == 0){
        s  = ps[0]+ps[1]+ps[2]+ps[3];
        sq = pq[0]+pq[1]+pq[2]+pq[3];
        float mean = s * (1.0f/DD);
        float var  = sq * (1.0f/DD) - mean*mean;
        sm = mean; sv = rsqrtf(var + 1e-5f);
    }
    __syncthreads();
    if (tid < 224){
        const float mean = sm, rstd = sv;
        float4 gg = *(const float4*)(g  + tid*4);
        float4 bb = *(const float4*)(bt + tid*4);
        float o0 = (v.x-mean)*rstd*gg.x + bb.x;
        float o1 = (v.y-mean)*rstd*gg.y + bb.y;
        float o2 = (v.z-mean)*rstd*gg.z + bb.z;
        float o3 = (v.w-mean)*rstd*gg.w + bb.w;
        unsigned h0,l0,h1,l1,h2,l2,h3,l3;
        split1(o0,h0,l0); split1(o1,h1,l1); split1(o2,h2,l2); split1(o3,h3,l3);
        *(uint2*)(H + (size_t)r*DD + tid*4) = make_uint2(h0|(h1<<16), h2|(h3<<16));
        *(uint2*)(L + (size_t)r*DD + tid*4) = make_uint2(l0|(l1<<16), l2|(l3<<16));
    }
}

// ---------------------------------------------------------------------------
// 3-term split-MFMA NT GEMM on PRE-SPLIT inputs (staging = pure copy).
// C[m,n] = sum_k A[m,k]*B[n,k], fp32-accurate via Ah*Bh + Ah*Bl + Al*Bh.
// BM = 32*MT, BN = 128, BK = 32.  4 waves (2m x 2n).
// MODE 0: enc epilogue  -> z[nn] = acc + stream_bias[nn], nn=0..3 (C, ldc)
// MODE 1: mix1 epilogue -> split(gelu(acc+bias)) -> Hh/Hl u16 (ldc = MIX)
// MODE 2: mix2 epilogue -> C += acc + bias (fp32, ldc)
// ---------------------------------------------------------------------------
template<int MODE, int MT>
__global__ __launch_bounds__(256, 2)
void mfma3(const u16* __restrict__ Ah, const u16* __restrict__ Al,
           const u16* __restrict__ Bh, const u16* __restrict__ Bl,
           int K, float* __restrict__ C, int ldc,
           u16* __restrict__ Hh, u16* __restrict__ Hl,
           const float* __restrict__ bias)
{
    constexpr int BM  = 32*MT;
    constexpr int AHo = 0;
    constexpr int ALo = BM*16;
    constexpr int BHo = 2*BM*16;
    constexpr int BLo = BHo + 2048;
    __shared__ uint4 smem4[(2*BM*16 + 4096)/4];
    unsigned int* smem = (unsigned int*)smem4;

    const int tid  = threadIdx.x;
    const int lane = tid & 63, wave = tid >> 6;
    const int wm = wave >> 1, wn = wave & 1;
    const int m0 = blockIdx.x * BM, n0 = blockIdx.y * 128;
    const int lr = lane & 15, lc = lane >> 4;

    f32x4 acc[MT][4];
    #pragma unroll
    for (int mi=0;mi<MT;mi++)
        #pragma unroll
        for (int ni=0;ni<4;ni++) acc[mi][ni] = (f32x4){0.f,0.f,0.f,0.f};

    for (int k0 = 0; k0 < K; k0 += 32){
        __syncthreads();
        #pragma unroll
        for (int it = 0; it < MT/2; ++it){
            const int pos = tid + it*256;
            const int R = pos >> 2, Cc = pos & 3;
            const int ad = R*16 + ((Cc ^ ((R>>1)&3)) << 2);
            const size_t go = (size_t)(m0 + R)*K + k0 + Cc*8;
            *(uint4*)&smem[AHo + ad] = *(const uint4*)(Ah + go);
            *(uint4*)&smem[ALo + ad] = *(const uint4*)(Al + go);
        }
        #pragma unroll
        for (int it = 0; it < 2; ++it){
            const int pos = tid + it*256;
            const int R = pos >> 2, Cc = pos & 3;
            const int ad = R*16 + ((Cc ^ ((R>>1)&3)) << 2);
            const size_t go = (size_t)(n0 + R)*K + k0 + Cc*8;
            *(uint4*)&smem[BHo + ad] = *(const uint4*)(Bh + go);
            *(uint4*)&smem[BLo + ad] = *(const uint4*)(Bl + go);
        }
        __syncthreads();
        bf16x8 ah[MT], al[MT], bh[4], bl[4];
        #pragma unroll
        for (int mi=0; mi<MT; ++mi){
            const int ar = wm*(16*MT) + mi*16 + lr;
            const int ad = ar*16 + ((lc ^ ((ar>>1)&3)) << 2);
            ah[mi] = *reinterpret_cast<const bf16x8*>(&smem[AHo + ad]);
            al[mi] = *reinterpret_cast<const bf16x8*>(&smem[ALo + ad]);
        }
        #pragma unroll
        for (int ni=0; ni<4; ++ni){
            const int br = wn*64 + ni*16 + lr;
            const int ad = br*16 + ((lc ^ ((br>>1)&3)) << 2);
            bh[ni] = *reinterpret_cast<const bf16x8*>(&smem[BHo + ad]);
            bl[ni] = *reinterpret_cast<const bf16x8*>(&smem[BLo + ad]);
        }
        #pragma unroll
        for (int mi=0; mi<MT; ++mi)
            #pragma unroll
            for (int ni=0; ni<4; ++ni){
                acc[mi][ni] = __builtin_amdgcn_mfma_f32_16x16x32_bf16(ah[mi], bh[ni], acc[mi][ni], 0,0,0);
                acc[mi][ni] = __builtin_amdgcn_mfma_f32_16x16x32_bf16(ah[mi], bl[ni], acc[mi][ni], 0,0,0);
                acc[mi][ni] = __builtin_amdgcn_mfma_f32_16x16x32_bf16(al[mi], bh[ni], acc[mi][ni], 0,0,0);
            }
    }
    // epilogue: C/D layout col = lane&15, row = (lane>>4)*4 + q  [m89]
    if (MODE == 0){
        #pragma unroll
        for (int nn = 0; nn < NSTREAM; ++nn){
            #pragma unroll
            for (int ni=0; ni<4; ++ni){
                const int col = n0 + wn*64 + ni*16 + lr;
                const float sb = bias[nn*DD + col];
                #pragma unroll
                for (int mi=0; mi<MT; ++mi)
                    #pragma unroll
                    for (int q=0;q<4;q++){
                        const int row = m0 + wm*(16*MT) + mi*16 + lc*4 + q;
                        C[(size_t)(nn*BT + row)*ldc + col] = acc[mi][ni][q] + sb;
                    }
            }
        }
    } else if (MODE == 1){
        #pragma unroll
        for (int ni=0; ni<4; ++ni){
            const int col = n0 + wn*64 + ni*16 + lr;
            const float bb = bias[col];
            #pragma unroll
            for (int mi=0; mi<MT; ++mi)
                #pragma unroll
                for (int q=0;q<4;q++){
                    const int row = m0 + wm*(16*MT) + mi*16 + lc*4 + q;
                    const float vv = gelu_exact(acc[mi][ni][q] + bb);
                    unsigned h, l; split1(vv, h, l);
                    Hh[(size_t)row*ldc + col] = (u16)h;
                    Hl[(size_t)row*ldc + col] = (u16)l;
                }
        }
    } else {
        #pragma unroll
        for (int ni=0; ni<4; ++ni){
            const int col = n0 + wn*64 + ni*16 + lr;
            const float bb = bias[col];
            #pragma unroll
            for (int mi=0; mi<MT; ++mi)
                #pragma unroll
                for (int q=0;q<4;q++){
                    const int row = m0 + wm*(16*MT) + mi*16 + lc*4 + q;
                    C[(size_t)row*ldc + col] += acc[mi][ni][q] + bb;
                }
        }
    }
}

// ---------------------------------------------------------------------------
// Weight transpose+split: W[12][896][128] -> wt_hi/lo[3][12][128][896] bf16.
// ---------------------------------------------------------------------------
__global__ __launch_bounds__(256)
void wt_split(const float* __restrict__ Wq, const float* __restrict__ Wk,
              const float* __restrict__ Wv, u16* __restrict__ wh, u16* __restrict__ wl)
{
    __shared__ float ftile[32][132];
    const int tid = threadIdx.x;
    const int widx = blockIdx.x, k0 = blockIdx.y*32, which = blockIdx.z;
    const float* W = (which==0 ? Wq : which==1 ? Wk : Wv) + (size_t)widx*DD*DH;
    #pragma unroll
    for (int it=0; it<4; ++it){
        const int pos = tid + it*256;
        const int r = pos >> 5, c4 = (pos & 31)*4;
        float4 v = *(const float4*)(W + (size_t)(k0+r)*DH + c4);
        *(float4*)&ftile[r][c4] = v;
    }
    __syncthreads();
    const int ct = tid >> 1, kseg = (tid & 1)*16;
    unsigned hi[8], lo[8];
    #pragma unroll
    for (int jj=0; jj<8; ++jj){
        unsigned h0,l0,h1,l1;
        split1(ftile[kseg+2*jj  ][ct], h0, l0);
        split1(ftile[kseg+2*jj+1][ct], h1, l1);
        hi[jj] = h0 | (h1<<16);  lo[jj] = l0 | (l1<<16);
    }
    u16* op = wh + ((size_t)((which*12+widx)*128 + ct))*DD + k0 + kseg;
    *(uint4*)op     = make_uint4(hi[0],hi[1],hi[2],hi[3]);
    *(uint4*)(op+8) = make_uint4(hi[4],hi[5],hi[6],hi[7]);
    u16* ol = wl + ((size_t)((which*12+widx)*128 + ct))*DD + k0 + kseg;
    *(uint4*)ol     = make_uint4(lo[0],lo[1],lo[2],lo[3]);
    *(uint4*)(ol+8) = make_uint4(lo[4],lo[5],lo[6],lo[7]);
}

// ---------------------------------------------------------------------------
// QKV projection for ONE stream, 3-term split (round-4-proven accuracy):
// A = pre-split LN'd z (zah/zal), B = pre-split weights.  grid (32, 9).
// Epilogue: head-scramble bf16 store h=n*3+(3t+kh)/1024, p=(3t+kh)%1024.
// ---------------------------------------------------------------------------
__global__ __launch_bounds__(256, 2)
void qkv3(const u16* __restrict__ zah, const u16* __restrict__ zal,
          const u16* __restrict__ wh, const u16* __restrict__ wl, int n,
          u16* __restrict__ qo, u16* __restrict__ ko, u16* __restrict__ vo)
{
    constexpr int AHo = 0, ALo = 2048, BHo = 4096, BLo = 6144;
    __shared__ uint4 smem4[8192/4];
    unsigned int* smem = (unsigned int*)smem4;

    const int tid  = threadIdx.x;
    const int lane = tid & 63, wave = tid >> 6;
    const int wm = wave >> 1, wn = wave & 1;
    const int lr = lane & 15, lc = lane >> 4;
    const int m0 = blockIdx.x * 128;
    const int which = blockIdx.y / 3, kh = blockIdx.y % 3;
    const u16* Bh = wh + (size_t)(which*12 + kh*4 + n) * 128 * DD;
    const u16* Bl = wl + (size_t)(which*12 + kh*4 + n) * 128 * DD;
    u16* Op = (which==0 ? qo : which==1 ? ko : vo);

    f32x4 acc[4][4];
    #pragma unroll
    for (int mi=0;mi<4;mi++)
        #pragma unroll
        for (int ni=0;ni<4;ni++) acc[mi][ni] = (f32x4){0.f,0.f,0.f,0.f};

    for (int k0 = 0; k0 < DD; k0 += 32){
        __syncthreads();
        #pragma unroll
        for (int it = 0; it < 2; ++it){
            const int pos = tid + it*256;
            const int R = pos >> 2, Cc = pos & 3;
            const int ad = R*16 + ((Cc ^ ((R>>1)&3)) << 2);
            const size_t go = (size_t)(m0 + R)*DD + k0 + Cc*8;
            *(uint4*)&smem[AHo + ad] = *(const uint4*)(zah + go);
            *(uint4*)&smem[ALo + ad] = *(const uint4*)(zal + go);
        }
        #pragma unroll
        for (int it = 0; it < 2; ++it){
            const int pos = tid + it*256;
            const int R = pos >> 2, Cc = pos & 3;
            const int ad = R*16 + ((Cc ^ ((R>>1)&3)) << 2);
            const size_t go = (size_t)R*DD + k0 + Cc*8;
            *(uint4*)&smem[BHo + ad] = *(const uint4*)(Bh + go);
            *(uint4*)&smem[BLo + ad] = *(const uint4*)(Bl + go);
        }
        __syncthreads();
        bf16x8 ah[4], al[4], bh[4], bl[4];
        #pragma unroll
        for (int mi=0; mi<4; ++mi){
            const int ar = wm*64 + mi*16 + lr;
            const int ad = ar*16 + ((lc ^ ((ar>>1)&3)) << 2);
            ah[mi] = *reinterpret_cast<const bf16x8*>(&smem[AHo + ad]);
            al[mi] = *reinterpret_cast<const bf16x8*>(&smem[ALo + ad]);
        }
        #pragma unroll
        for (int ni=0; ni<4; ++ni){
            const int br = wn*64 + ni*16 + lr;
            const int ad = br*16 + ((lc ^ ((br>>1)&3)) << 2);
            bh[ni] = *reinterpret_cast<const bf16x8*>(&smem[BHo + ad]);
            bl[ni] = *reinterpret_cast<const bf16x8*>(&smem[BLo + ad]);
        }
        #pragma unroll
        for (int mi=0; mi<4; ++mi)
            #pragma unroll
            for (int ni=0; ni<4; ++ni){
                acc[mi][ni] = __builtin_amdgcn_mfma_f32_16x16x32_bf16(ah[mi], bh[ni], acc[mi][ni], 0,0,0);
                acc[mi][ni] = __builtin_amdgcn_mfma_f32_16x16x32_bf16(ah[mi], bl[ni], acc[mi][ni], 0,0,0);
                acc[mi][ni] = __builtin_amdgcn_mfma_f32_16x16x32_bf16(al[mi], bh[ni], acc[mi][ni], 0,0,0);
            }
    }
    #pragma unroll
    for (int mi=0; mi<4; ++mi){
        #pragma unroll
        for (int q=0;q<4;q++){
            const int m = m0 + wm*64 + mi*16 + lc*4 + q;
            const int b = m >> 10, t = m & 1023;
            const int v3 = 3*t + kh;
            const int c = v3 >> 10, p = v3 & 1023;
            u16* op = Op + ((size_t)((b*HH + n*KHEADS + c)*TT + p))*DH;
            #pragma unroll
            for (int ni=0; ni<4; ++ni){
                const int col = wn*64 + ni*16 + lr;
                op[col] = bf16r(acc[mi][ni][q]);
            }
        }
    }
}

// ---------------------------------------------------------------------------
// Flash attention, bf16 MFMA (PROVEN round 4).  Writes fp32 into d_out at
// the scattered active-slot location.
// ---------------------------------------------------------------------------
__global__ __launch_bounds__(256)
void flash_mfma(const u16* __restrict__ qb, const u16* __restrict__ kb,
                const u16* __restrict__ vb, float* __restrict__ Out,
                const int* __restrict__ causal_p)
{
    __shared__ u16 lds[8192 + 8192 + 4608];
    u16* Ks = lds;
    u16* Vt = lds + 8192;
    u16* Pl = lds + 16384;
    const int tid = threadIdx.x, lane = tid & 63, wv = tid >> 6;
    const int lr = lane & 15, lc = lane >> 4;
    const int qt = (int)gridDim.x - 1 - (int)blockIdx.x;
    const int h = blockIdx.y, b = blockIdx.z;
    const int causal = causal_p[0];
    const int n = h / KHEADS, c = h % KHEADS;
    const int s_off = (c == 2 ? 3 : c) * DH;
    const size_t base = (size_t)(b*HH + h) * TT * DH;
    const float scl = 0.08838834764831845f;

    uint4 qf[4];
    const int qrow = qt*64 + wv*16 + lr;
    #pragma unroll
    for (int kc=0; kc<4; ++kc)
        qf[kc] = *(const uint4*)(qb + base + (size_t)qrow*DH + kc*32 + lc*8);

    f32x4 o[8];
    #pragma unroll
    for (int i=0;i<8;i++) o[i] = (f32x4){0.f,0.f,0.f,0.f};
    float mi[4], li[4];
    #pragma unroll
    for (int j=0;j<4;j++){ mi[j] = -1e30f; li[j] = 0.f; }

    const int nkt = causal ? (qt + 1) : 16;
    for (int kt = 0; kt < nkt; ++kt){
        __syncthreads();
        #pragma unroll
        for (int it=0; it<4; ++it){
            const int pos = tid + it*256;
            const int key = pos >> 4, sc = pos & 15;
            uint4 v = *(const uint4*)(kb + base + (size_t)(kt*64+key)*DH + sc*8);
            const int kc = sc >> 2, cc = sc & 3;
            const int word = key*64 + ((kc ^ (key&3))<<4) + ((cc ^ ((key>>2)&3))<<2);
            *(uint4*)(Ks + word*2) = v;
        }
        #pragma unroll
        for (int it=0; it<4; ++it){
            const int pos = tid + it*256;
            const int sc = pos >> 6, key = pos & 63;
            uint4 v = *(const uint4*)(vb + base + (size_t)(kt*64+key)*DH + sc*8);
            const u16* e = (const u16*)&v;
            const int kcv = key>>5, cv = (key>>3)&3, w_ = (key>>1)&3, half = key&1;
            #pragma unroll
            for (int j=0;j<8;++j){
                const int dh = sc*8 + j;
                const int word = dh*32 + ((kcv ^ (dh&1))<<4) + ((cv ^ ((dh>>1)&3))<<2) + w_;
                Vt[word*2 + half] = e[j];
            }
        }
        __syncthreads();
        f32x4 s[4];
        #pragma unroll
        for (int nk=0;nk<4;nk++) s[nk] = (f32x4){0.f,0.f,0.f,0.f};
        #pragma unroll
        for (int kc=0; kc<4; ++kc){
            #pragma unroll
            for (int nk=0; nk<4; ++nk){
                const int key = nk*16 + lr;
                const int word = key*64 + ((kc ^ (key&3))<<4) + ((lc ^ ((key>>2)&3))<<2);
                uint4 kf = *(const uint4*)(Ks + word*2);
                s[nk] = __builtin_amdgcn_mfma_f32_16x16x32_bf16(as_bf(qf[kc]), as_bf(kf), s[nk], 0,0,0);
            }
        }
        #pragma unroll
        for (int nk=0;nk<4;nk++){
            s[nk][0]*=scl; s[nk][1]*=scl; s[nk][2]*=scl; s[nk][3]*=scl;
        }
        if (causal && kt == qt){
            #pragma unroll
            for (int nk=0;nk<4;nk++){
                const int keyg = kt*64 + nk*16 + lr;
                #pragma unroll
                for (int j=0;j<4;j++){
                    const int qg = qt*64 + wv*16 + lc*4 + j;
                    if (keyg > qg) s[nk][j] = -1e30f;
                }
            }
        }
        #pragma unroll
        for (int j=0;j<4;j++){
            float mx = fmaxf(fmaxf(s[0][j], s[1][j]), fmaxf(s[2][j], s[3][j]));
            #pragma unroll
            for (int off=1; off<16; off<<=1) mx = fmaxf(mx, __shfl_xor(mx, off));
            const float mnew = fmaxf(mi[j], mx);
            const float corr = __expf(mi[j] - mnew);
            float p0 = __expf(s[0][j]-mnew), p1 = __expf(s[1][j]-mnew);
            float p2 = __expf(s[2][j]-mnew), p3 = __expf(s[3][j]-mnew);
            float rs = p0+p1+p2+p3;
            #pragma unroll
            for (int off=1; off<16; off<<=1) rs += __shfl_xor(rs, off);
            li[j] = li[j]*corr + rs;
            mi[j] = mnew;
            #pragma unroll
            for (int ni=0;ni<8;ni++) o[ni][j] *= corr;
            const int prow = lc*4 + j;
            u16* pw = Pl + wv*1152 + prow*72;
            pw[lr]      = bf16r(p0);
            pw[16 + lr] = bf16r(p1);
            pw[32 + lr] = bf16r(p2);
            pw[48 + lr] = bf16r(p3);
        }
        uint4 pf[2];
        #pragma unroll
        for (int kc2=0; kc2<2; ++kc2)
            pf[kc2] = *(const uint4*)(Pl + wv*1152 + lr*72 + kc2*32 + lc*8);
        #pragma unroll
        for (int kc2=0; kc2<2; ++kc2){
            #pragma unroll
            for (int ni=0; ni<8; ++ni){
                const int dh = ni*16 + lr;
                const int word = dh*32 + ((kc2 ^ (dh&1))<<4) + ((lc ^ ((dh>>1)&3))<<2);
                uint4 vf = *(const uint4*)(Vt + word*2);
                o[ni] = __builtin_amdgcn_mfma_f32_16x16x32_bf16(as_bf(pf[kc2]), as_bf(vf), o[ni], 0,0,0);
            }
        }
    }
    float inv[4];
    #pragma unroll
    for (int j=0;j<4;j++) inv[j] = 1.0f / li[j];
    #pragma unroll
    for (int j=0;j<4;j++){
        const int p = qt*64 + wv*16 + lc*4 + j;
        float* op = Out + ((size_t)((n*BB + b)*TT + p))*DD + s_off;
        #pragma unroll
        for (int ni=0; ni<8; ++ni)
            op[ni*16 + lr] = o[ni][j] * inv[j];
    }
}

// ---------------------------------------------------------------------------
// Final assembly (in-place on d_out): out = z + (active slot ? out : 0)
// ---------------------------------------------------------------------------
__global__ __launch_bounds__(256)
void assemble(const float* __restrict__ Z, float* __restrict__ out)
{
    const int idx = blockIdx.x * 256 + threadIdx.x;
    const int d4 = idx % 224;
    const size_t loc = (size_t)idx * 4;
    const int s = d4 >> 5;
    float4 v = *(const float4*)(Z + loc);
    if (s == 0 || s == 1 || s == 3){
        const float4 a = *(const float4*)(out + loc);
        v.x += a.x; v.y += a.y; v.z += a.z; v.w += a.w;
    }
    *(float4*)(out + loc) = v;
}

// ---------------------------------------------------------------------------
extern "C" void kernel_launch(void* const* d_in, const int* in_sizes, int n_in,
                              void* d_out, int out_size, void* d_ws, size_t ws_size,
                              hipStream_t stream)
{
    (void)in_sizes; (void)n_in; (void)out_size; (void)ws_size;
    const float* x           = (const float*)d_in[0];
    const float* enc_W       = (const float*)d_in[1];
    const float* stream_bias = (const float*)d_in[2];
    const float* ln_mix_g    = (const float*)d_in[3];
    const float* ln_mix_b    = (const float*)d_in[4];
    const float* W1          = (const float*)d_in[5];
    const float* b1          = (const float*)d_in[6];
    const float* W2          = (const float*)d_in[7];
    const float* b2          = (const float*)d_in[8];
    const float* ln_attn_g   = (const float*)d_in[9];
    const float* ln_attn_b   = (const float*)d_in[10];
    const float* Wq          = (const float*)d_in[11];
    const float* Wk          = (const float*)d_in[12];
    const float* Wv          = (const float*)d_in[13];
    const int*   is_causal   = (const int*)d_in[15];
    float* out = (float*)d_out;

    // ws: z (14,680,064 f32 = 58.7MB) | r2 (34,867,712 u16 = 69.7MB) = 128.5MB
    float* z  = (float*)d_ws;
    u16*   r2 = (u16*)(z + ZSZ);
    // MLP-phase (u16 offsets; sizes: w1/w2 3,211,264; a 3,670,016; h 7,340,032)
    u16* w1h = r2;                  // [0 .. 3,211,264)
    u16* w1l = r2 + 3211264;
    u16* w2h = r2 + 6422528;
    u16* w2l = r2 + 9633792;        // ends 12,845,056
    u16* ahi = r2 + 12845056;       // ends 16,515,072
    u16* alo = r2 + 16516352;       // ends 20,186,368 (1,280 gap ok)
    u16* hhi = r2 + 20187648;       // ends 27,527,680
    u16* hlo = r2 + 27527680;       // ends 34,867,712  (FIXED: was 27,527,424 -> overlapped hhi by 256)
    // enc-phase (aliases a/h region, dead before MLP)
    u16* xh  = r2 + 12845056;       // 3,145,728 -> ends 15,990,784
    u16* xl  = r2 + 15990784;       // ends 19,136,512
    u16* ewh = r2 + 20187648;       // 688,128 -> ends 20,875,776
    u16* ewl = r2 + 20875776;       // ends 21,563,904
    // qkv-phase (aliases everything; all MLP buffers dead)
    u16* wqh = r2;                  // 4,128,768 -> ends 4,128,768
    u16* wql = r2 + 4128768;        // ends 8,257,536
    u16* zah = r2 + 8257536;        // 3,670,016 -> ends 11,927,552
    u16* zal = r2 + 11927552;       // ends 15,597,568
    u16* qb  = r2 + 15597568;       // 6,291,456 -> ends 21,889,024
    u16* kb  = r2 + 21889024;       // ends 28,180,480
    u16* vb  = r2 + 28180480;       // ends 34,471,936
    dim3 blk(256);

    // 1) pre-split enc inputs + MLP weights
    split_pair<<<1536, blk, 0, stream>>>(x,     xh,  xl,  3145728/8);
    split_pair<<< 336, blk, 0, stream>>>(enc_W, ewh, ewl,  688128/8);
    split_pair<<<1568, blk, 0, stream>>>(W1,    w1h, w1l, 3211264/8);
    split_pair<<<1568, blk, 0, stream>>>(W2,    w2h, w2l, 3211264/8);
    // 2) enc GEMM (split-MFMA) + stream-bias fan-out
    mfma3<0,4><<<dim3(32, 7), blk, 0, stream>>>(xh, xl, ewh, ewl, IO,
                                                z, DD, nullptr, nullptr, stream_bias);
    // 3) per-stream MLP: fused LN+split, then GEMM1/GEMM2 in half-chunks
    for (int nn = 0; nn < NSTREAM; ++nn){
        float* zs = z + (size_t)nn*BT*DD;
        ln_split<<<BT, blk, 0, stream>>>(zs, ln_mix_g, ln_mix_b, ahi, alo);
        for (int half = 0; half < 2; ++half){
            const size_t ao = (size_t)half*2048*DD;
            mfma3<1,4><<<dim3(16, 28), blk, 0, stream>>>(
                ahi + ao, alo + ao, w1h, w1l, DD,
                nullptr, MIX, hhi, hlo, b1);
            mfma3<2,2><<<dim3(32, 7), blk, 0, stream>>>(
                hhi, hlo, w2h, w2l, MIX,
                zs + ao, DD, nullptr, nullptr, b2);
        }
    }
    // 4) QKV weight transpose+split (overwrites dead W1/W2 splits)
    wt_split<<<dim3(12, 28, 3), blk, 0, stream>>>(Wq, Wk, Wv, wqh, wql);
    // 5) per-stream attn-LN+split, then 3-term QKV projections
    for (int nn = 0; nn < NSTREAM; ++nn){
        ln_split<<<BT, blk, 0, stream>>>(z + (size_t)nn*BT*DD,
                                         ln_attn_g, ln_attn_b, zah, zal);
        qkv3<<<dim3(32, 9), blk, 0, stream>>>(zah, zal, wqh, wql, nn, qb, kb, vb);
    }
    // 6) causal flash attention -> writes into d_out active slots
    flash_mfma<<<dim3(16, HH, BB), blk, 0, stream>>>(qb, kb, vb, out, is_causal);
    // 7) residual + inactive-slot fill, in place on d_out
    assemble<<<ZSZ/4/256, blk, 0, stream>>>(z, out);
}